// Round 4
// baseline (942.147 us; speedup 1.0000x reference)
//
#include <hip/hip_runtime.h>
#include <hip/hip_cooperative_groups.h>
#include <math.h>

#define NN 40000
#define HD 128
#define NE 640000
#define MINN 1e-15f
#define NSB 157       // ceil(NN/256) scan chunks
#define GB  2500      // 16-row tiles
#define NBLK 256
#define NTHR 512
#define NWAVE 2048    // NBLK * 8 waves

typedef __attribute__((ext_vector_type(8))) short bf16x8;
typedef __attribute__((ext_vector_type(4))) float f32x4;

namespace cg = cooperative_groups;

__device__ __forceinline__ float red16(float v){
  v += __shfl_xor(v, 1, 64); v += __shfl_xor(v, 2, 64);
  v += __shfl_xor(v, 4, 64); v += __shfl_xor(v, 8, 64);
  return v;
}

__device__ __forceinline__ float bf2f(short h){
  return __uint_as_float(((unsigned)(unsigned short)h) << 16);
}
__device__ __forceinline__ short f2bf(float v){
  unsigned u = __float_as_uint(v);
  u += 0x7FFF + ((u >> 16) & 1);       // RNE
  return (short)(u >> 16);
}

// gather accumulate: 8 bf16 cols from one uint4 row-chunk
#define GACC(A,V) \
  A[0] += __uint_as_float((V).x << 16); A[1] += __uint_as_float((V).x & 0xffff0000u); \
  A[2] += __uint_as_float((V).y << 16); A[3] += __uint_as_float((V).y & 0xffff0000u); \
  A[4] += __uint_as_float((V).z << 16); A[5] += __uint_as_float((V).z & 0xffff0000u); \
  A[6] += __uint_as_float((V).w << 16); A[7] += __uint_as_float((V).w & 0xffff0000u);

struct KParams {
  const float *x; const int *ei;
  const float *fc0_w, *fc0_b, *w1, *b1, *gamma, *beta, *w2, *b2, *fco_w, *fco_b, *p;
  float *out;
  float *h, *zA, *zB, *t, *part;
  bf16x8 *bhi, *blo;
  unsigned short *hb;
  int *cnt, *ptr, *fil;
  unsigned short *eidx;
  int *locpre, *btot, *boff;
  float scaling;
};

// ---- A rows (rb+l15, cols ks*32+kg*8..+8) from global row-major [.,128] ----
__device__ __forceinline__ void loadA_g(const float* A, long rb, int l15, int kg,
                                        float av[4][8]){
  #pragma unroll
  for (int ks = 0; ks < 4; ++ks){
    const float* ap = A + (rb + l15)*HD + ks*32 + kg*8;
    float4 a0 = *(const float4*)ap;
    float4 a1 = *(const float4*)(ap + 4);
    av[ks][0]=a0.x; av[ks][1]=a0.y; av[ks][2]=a0.z; av[ks][3]=a0.w;
    av[ks][4]=a1.x; av[ks][5]=a1.y; av[ks][6]=a1.z; av[ks][7]=a1.w;
  }
}

// ---- split-bf16 3-term MFMA: acc = A(f32 via hi+lo) @ W^T ----
__device__ __forceinline__ void mfma_core(const float av[4][8],
    const bf16x8* bh, const bf16x8* bl, int lane, f32x4 acc[8]){
  #pragma unroll
  for (int ct = 0; ct < 8; ++ct){
    acc[ct][0]=0.f; acc[ct][1]=0.f; acc[ct][2]=0.f; acc[ct][3]=0.f;
  }
  #pragma unroll
  for (int ks = 0; ks < 4; ++ks){
    bf16x8 ah, al;
    #pragma unroll
    for (int j = 0; j < 8; ++j){
      float v = av[ks][j];
      short hh = f2bf(v);
      short ll = f2bf(v - bf2f(hh));
      ah[j] = hh; al[j] = ll;
    }
    #pragma unroll
    for (int ct = 0; ct < 8; ++ct){
      bf16x8 bhv = bh[(ks*8 + ct)*64 + lane];
      bf16x8 blv = bl[(ks*8 + ct)*64 + lane];
      acc[ct] = __builtin_amdgcn_mfma_f32_16x16x32_bf16(ah, bhv, acc[ct], 0, 0, 0);
      acc[ct] = __builtin_amdgcn_mfma_f32_16x16x32_bf16(al, bhv, acc[ct], 0, 0, 0);
      acc[ct] = __builtin_amdgcn_mfma_f32_16x16x32_bf16(ah, blv, acc[ct], 0, 0, 0);
    }
  }
}

__device__ __forceinline__ void biasrelu(f32x4 acc[8], const float* bias, int l15,
                                         bool relu){
  #pragma unroll
  for (int ct = 0; ct < 8; ++ct){
    float bb = bias[ct*16 + l15];
    #pragma unroll
    for (int q = 0; q < 4; ++q){
      float v = acc[ct][q] + bb;
      if (relu) v = fmaxf(v, 0.f);
      acc[ct][q] = v;
    }
  }
}

// ---- full hyperbolic z-update (zp aliases zo; read-before-write per row) ----
__device__ __forceinline__ void zstep_f(const f32x4 acc[8], float* zo,
    const float* zc_, const float* pvec, float scaling, long rb, int kg, int l15,
    bool first){
  float pv[8]; float pq = 0.f;
  #pragma unroll
  for (int ct = 0; ct < 8; ++ct){
    float tv = pvec[ct*16 + l15];
    pv[ct] = tv; pq = fmaf(tv, tv, pq);
  }
  pq = red16(pq);
  float qi = 1.0f / fmaxf(sqrtf(pq), MINN);
  #pragma unroll
  for (int ct = 0; ct < 8; ++ct) pv[ct] *= qi;

  #pragma unroll
  for (int q = 0; q < 4; ++q){
    const long row = rb + kg*4 + q;
    float zc[8], zp[8];
    #pragma unroll
    for (int ct = 0; ct < 8; ++ct) zc[ct] = zc_[row*HD + ct*16 + l15];
    if (first){
      #pragma unroll
      for (int ct = 0; ct < 8; ++ct) zp[ct] = 0.f;
    } else {
      #pragma unroll
      for (int ct = 0; ct < 8; ++ct) zp[ct] = zo[row*HD + ct*16 + l15];
    }
    float hh = 0.f, cc = 0.f;
    #pragma unroll
    for (int ct = 0; ct < 8; ++ct){
      hh = fmaf(acc[ct][q], acc[ct][q], hh);
      cc = fmaf(zc[ct], zc[ct], cc);
    }
    hh = red16(hh); cc = red16(cc);
    float zs = scaling / sqrtf(hh);
    float di = 1.0f / fmaxf(cc, MINN);
    float r2 = cc*di*di - 1.0f;
    float a[8], u[8]; float uu = 0.f;
    #pragma unroll
    for (int ct = 0; ct < 8; ++ct){
      a[ct] = zc[ct]*di;
      u[ct] = zp[ct] - a[ct];
      uu = fmaf(u[ct], u[ct], uu);
    }
    uu = red16(uu);
    float f = r2 / fmaxf(uu, MINN);
    float zpar[8]; float pn2 = 0.f;
    #pragma unroll
    for (int ct = 0; ct < 8; ++ct){
      zpar[ct] = fmaf(f, u[ct], a[ct]);
      pn2 = fmaf(zpar[ct], zpar[ct], pn2);
    }
    pn2 = red16(pn2);
    float pinv = 1.0f / fmaxf(sqrtf(pn2), MINN);
    float rv[8], zch[8]; float rz = 0.f, rr = 0.f;
    #pragma unroll
    for (int ct = 0; ct < 8; ++ct){
      zch[ct] = acc[ct][q]*zs;
      rv[ct] = pv[ct] - zpar[ct]*pinv;
      rz = fmaf(rv[ct], zch[ct], rz);
      rr = fmaf(rv[ct], rv[ct], rr);
    }
    rz = red16(rz); rr = red16(rr);
    float mm = rz / rr;
    float u2[8]; float uu2 = 0.f;
    #pragma unroll
    for (int ct = 0; ct < 8; ++ct){
      float z2 = fmaf(-2.0f*mm, rv[ct], zch[ct]);
      u2[ct] = z2 - a[ct];
      uu2 = fmaf(u2[ct], u2[ct], uu2);
    }
    uu2 = red16(uu2);
    float f2 = r2 / fmaxf(uu2, MINN);
    #pragma unroll
    for (int ct = 0; ct < 8; ++ct)
      zo[row*HD + ct*16 + l15] = fmaf(f2, u2[ct], a[ct]);
  }
}

// =================== ONE cooperative kernel: whole pipeline ===================
__global__ __launch_bounds__(NTHR, 2) void fused_k(KParams prm){
  cg::grid_group gg = cg::this_grid();
  const int tid  = threadIdx.x;
  const int bid  = blockIdx.x;
  const int gid  = bid*NTHR + tid;
  const int lane = tid & 63;
  const int wv   = tid >> 6;
  const int l15  = lane & 15, kg = lane >> 4;
  const int wgid = bid*8 + wv;

  __shared__ float gtl[8*16*132];   // wave-private gather slices (67.6 KB)
  __shared__ float stats[8*256];    // per-wave BN stats rows / BN totals
  __shared__ float bns[256];        // scale[0..127], shift[128..255]
  __shared__ int   si[256];         // scan scratch

  const int* src = prm.ei;
  const int* dst = prm.ei + NE;
  const uint4* hb4 = (const uint4*)prm.hb;

  // ---------- P0: zero cnt + weight prep (split bf16 hi/lo, B-fragment order) ----------
  for (int i2 = gid; i2 < NN; i2 += NBLK*NTHR) prm.cnt[i2] = 0;
  if (gid < 16384){
    int widx = gid >> 11;
    const float* W;
    if (widx == 0)      W = prm.fc0_w;
    else if (widx <= 3) W = prm.w1 + (size_t)(widx-1)*HD*HD;
    else if (widx <= 6) W = prm.w2 + (size_t)(widx-4)*HD*HD;
    else                W = prm.fco_w;
    int f  = gid & 2047;
    int ln = f & 63;
    int ct = (f >> 6) & 7;
    int ks = f >> 9;
    int n  = ct*16 + (ln & 15);
    int k0 = ks*32 + (ln >> 4)*8;
    bf16x8 hv, lv;
    #pragma unroll
    for (int j = 0; j < 8; ++j){
      float v = W[n*HD + k0 + j];
      short hh = f2bf(v);
      short ll = f2bf(v - bf2f(hh));
      hv[j] = hh; lv[j] = ll;
    }
    prm.bhi[widx*2048 + f] = hv; prm.blo[widx*2048 + f] = lv;
  }
  gg.sync();

  // ---------- P1: histogram edges by dst ----------
  for (int e = gid; e < NE; e += NBLK*NTHR) atomicAdd(&prm.cnt[dst[e]], 1);
  gg.sync();

  // ---------- P2: per-chunk inclusive scan (blocks 0..156, threads 0..255) ----------
  {
    bool act = (bid < NSB) && (tid < 256);
    int idx = bid*256 + tid;
    int v = 0;
    if (act){ v = (idx < NN) ? prm.cnt[idx] : 0; si[tid] = v; }
    __syncthreads();
    for (int off = 1; off < 256; off <<= 1){
      int xv = 0;
      if (act && tid >= off) xv = si[tid-off];
      __syncthreads();
      if (act) si[tid] += xv;
      __syncthreads();
    }
    if (act){
      prm.locpre[idx] = si[tid] - v;
      if (tid == 255) prm.btot[bid] = si[255];
    }
  }
  gg.sync();

  // ---------- P3: scan of chunk totals (block 0) ----------
  if (bid == 0){
    bool act = tid < 256;
    int v = (tid < NSB) ? prm.btot[tid] : 0;
    if (act) si[tid] = v;
    __syncthreads();
    for (int off = 1; off < 256; off <<= 1){
      int xv = 0;
      if (act && tid >= off) xv = si[tid-off];
      __syncthreads();
      if (act) si[tid] += xv;
      __syncthreads();
    }
    if (tid < NSB) prm.boff[tid] = si[tid] - v;
    if (tid == NSB-1) prm.ptr[NN] = si[tid];
  }
  gg.sync();

  // ---------- P4: scatter row pointers ----------
  {
    int idx = bid*256 + tid;
    if (tid < 256 && idx < NN){
      int v = prm.boff[bid] + prm.locpre[idx];
      prm.ptr[idx] = v; prm.fil[idx] = v;
    }
  }
  gg.sync();

  // ---------- P5: fill edge buckets ----------
  for (int e = gid; e < NE; e += NBLK*NTHR){
    int d = dst[e];
    int pos = atomicAdd(&prm.fil[d], 1);
    prm.eidx[pos] = (unsigned short)src[e];
  }
  gg.sync();

  // ---------- P6: h = relu(x @ fc0_w^T + b) + bf16 mirror + zinit(zB) ----------
  for (int tile = wgid; tile < GB; tile += NWAVE){
    const long rb = (long)tile*16;
    float av[4][8]; loadA_g(prm.x, rb, l15, kg, av);
    f32x4 acc[8]; mfma_core(av, prm.bhi, prm.blo, lane, acc);
    biasrelu(acc, prm.fc0_b, l15, true);
    #pragma unroll
    for (int ct = 0; ct < 8; ++ct)
      #pragma unroll
      for (int q = 0; q < 4; ++q){
        float v = acc[ct][q];
        long row = rb + kg*4 + q;
        prm.h[row*HD + ct*16 + l15] = v;
        prm.hb[row*HD + ct*16 + l15] = (unsigned short)f2bf(v);
      }
    #pragma unroll
    for (int q = 0; q < 4; ++q){
      float ss = 0.f;
      #pragma unroll
      for (int ct = 0; ct < 8; ++ct) ss = fmaf(acc[ct][q], acc[ct][q], ss);
      ss = red16(ss);
      float sc2 = prm.scaling / sqrtf(ss);
      long row = rb + kg*4 + q;
      #pragma unroll
      for (int ct = 0; ct < 8; ++ct)
        prm.zB[row*HD + ct*16 + l15] = acc[ct][q]*sc2;
    }
  }
  gg.sync();

  // ---------- 3 GIN layers ----------
  for (int i = 0; i < 3; ++i){
    // ---- P7: t = relu((h + agg(h)) @ w1^T + b1), per-wave gather via LDS, stats ----
    {
      const bf16x8* bh = prm.bhi + (1+i)*2048;
      const bf16x8* bl = prm.blo + (1+i)*2048;
      const float* b1p = prm.b1 + i*HD;
      float ssum[8], sqq[8];
      #pragma unroll
      for (int ct = 0; ct < 8; ++ct){ ssum[ct] = 0.f; sqq[ct] = 0.f; }
      float* mytl = gtl + wv*(16*132);
      for (int tile = wgid; tile < GB; tile += NWAVE){
        const long rb = (long)tile*16;
        #pragma unroll
        for (int s5 = 0; s5 < 4; ++s5){
          const int r = kg*4 + s5;
          const long node = rb + r;
          int beg = prm.ptr[node], end = prm.ptr[node+1];
          const float4* selfp = (const float4*)(prm.h + node*HD) + l15*2;
          float4 s0 = selfp[0], s1 = selfp[1];
          float ga[8] = {s0.x,s0.y,s0.z,s0.w,s1.x,s1.y,s1.z,s1.w};
          int e = beg;
          for (; e + 4 <= end; e += 4){
            int i0 = prm.eidx[e],   i1 = prm.eidx[e+1];
            int i2 = prm.eidx[e+2], i3 = prm.eidx[e+3];
            uint4 v0 = hb4[(long)i0*16 + l15];
            uint4 v1 = hb4[(long)i1*16 + l15];
            uint4 v2 = hb4[(long)i2*16 + l15];
            uint4 v3 = hb4[(long)i3*16 + l15];
            GACC(ga,v0) GACC(ga,v1) GACC(ga,v2) GACC(ga,v3)
          }
          for (; e < end; ++e){
            uint4 v = hb4[(long)prm.eidx[e]*16 + l15];
            GACC(ga,v)
          }
          float4* tp = (float4*)(mytl + r*132 + l15*8);
          float4 o0 = {ga[0],ga[1],ga[2],ga[3]};
          float4 o1 = {ga[4],ga[5],ga[6],ga[7]};
          tp[0] = o0; tp[1] = o1;
        }
        float av[4][8];
        #pragma unroll
        for (int ks = 0; ks < 4; ++ks){
          const float* ap = mytl + l15*132 + ks*32 + kg*8;
          float4 a0 = *(const float4*)ap;
          float4 a1 = *(const float4*)(ap + 4);
          av[ks][0]=a0.x; av[ks][1]=a0.y; av[ks][2]=a0.z; av[ks][3]=a0.w;
          av[ks][4]=a1.x; av[ks][5]=a1.y; av[ks][6]=a1.z; av[ks][7]=a1.w;
        }
        f32x4 acc[8]; mfma_core(av, bh, bl, lane, acc);
        biasrelu(acc, b1p, l15, true);
        #pragma unroll
        for (int ct = 0; ct < 8; ++ct)
          #pragma unroll
          for (int q = 0; q < 4; ++q)
            prm.t[(rb + kg*4 + q)*HD + ct*16 + l15] = acc[ct][q];
        #pragma unroll
        for (int ct = 0; ct < 8; ++ct){
          float s = 0.f, q2 = 0.f;
          #pragma unroll
          for (int q = 0; q < 4; ++q){
            float v = acc[ct][q];
            s += v; q2 = fmaf(v, v, q2);
          }
          s  += __shfl_xor(s, 16, 64);  s  += __shfl_xor(s, 32, 64);
          q2 += __shfl_xor(q2, 16, 64); q2 += __shfl_xor(q2, 32, 64);
          ssum[ct] += s; sqq[ct] += q2;
        }
      }
      if (kg == 0){
        #pragma unroll
        for (int ct = 0; ct < 8; ++ct){
          stats[wv*256 + ct*16 + l15]       = ssum[ct];
          stats[wv*256 + 128 + ct*16 + l15] = sqq[ct];
        }
      }
      __syncthreads();
      if (tid < 256){
        float tot = 0.f;
        #pragma unroll
        for (int w = 0; w < 8; ++w) tot += stats[w*256 + tid];
        prm.part[bid*256 + tid] = tot;
      }
    }
    gg.sync();

    // ---- P8: BN finalize (block-local; every block reduces all 256 part rows) ----
    if (tid < 256){
      float tot = 0.f;
      for (int r = 0; r < 256; ++r) tot += prm.part[r*256 + tid];
      stats[tid] = tot;
    }
    __syncthreads();
    if (tid < 128){
      float s = stats[tid], q = stats[tid + 128];
      float mu  = s * (1.0f/NN);
      float var = q * (1.0f/NN) - mu*mu;
      float istd = rsqrtf(var + 1e-5f);
      float scv = prm.gamma[i*HD + tid]*istd;
      bns[tid]       = scv;
      bns[128 + tid] = fmaf(-mu, scv, prm.beta[i*HD + tid]);
    }
    __syncthreads();

    // ---- P9: h = relu(BN(t) @ w2^T + b2) + z-step ----
    {
      const float* zc_ = (i & 1) ? prm.zA : prm.zB;
      float*       zo_ = (i & 1) ? prm.zB : prm.zA;
      const bf16x8* bh2 = prm.bhi + (4+i)*2048;
      const bf16x8* bl2 = prm.blo + (4+i)*2048;
      const float* b2p = prm.b2 + i*HD;
      for (int tile = wgid; tile < GB; tile += NWAVE){
        const long rb = (long)tile*16;
        float av[4][8]; loadA_g(prm.t, rb, l15, kg, av);
        #pragma unroll
        for (int ks = 0; ks < 4; ++ks){
          const int k0 = ks*32 + kg*8;
          #pragma unroll
          for (int j = 0; j < 8; ++j)
            av[ks][j] = fmaf(av[ks][j], bns[k0 + j], bns[128 + k0 + j]);
        }
        f32x4 acc[8]; mfma_core(av, bh2, bl2, lane, acc);
        biasrelu(acc, b2p, l15, true);
        if (i < 2){
          #pragma unroll
          for (int ct = 0; ct < 8; ++ct)
            #pragma unroll
            for (int q = 0; q < 4; ++q){
              float v = acc[ct][q];
              long row = rb + kg*4 + q;
              prm.h[row*HD + ct*16 + l15] = v;
              prm.hb[row*HD + ct*16 + l15] = (unsigned short)f2bf(v);
            }
        }
        zstep_f(acc, zo_, zc_, prm.p, prm.scaling, rb, kg, l15, i == 0);
      }
    }
    gg.sync();
  }

  // ---------- P10: out = normalize(logmap0(zA) @ fco_w^T + b) ----------
  for (int tile = wgid; tile < GB; tile += NWAVE){
    const long rb = (long)tile*16;
    float av[4][8]; loadA_g(prm.zA, rb, l15, kg, av);
    // logmap0 scaling (row-wise, 64-lane reduce over kg groups)
    float ss = 0.f;
    #pragma unroll
    for (int ks = 0; ks < 4; ++ks)
      #pragma unroll
      for (int j = 0; j < 8; ++j)
        ss = fmaf(av[ks][j], av[ks][j], ss);
    ss += __shfl_xor(ss, 16, 64);
    ss += __shfl_xor(ss, 32, 64);
    float n = sqrtf(ss);
    float yn = fmaxf(n, MINN);
    float c = fminf(yn, 1.0f);
    float at = 0.5f*logf((1.0f + c)/(1.0f - c));
    float scx = at / yn;
    #pragma unroll
    for (int ks = 0; ks < 4; ++ks)
      #pragma unroll
      for (int j = 0; j < 8; ++j)
        av[ks][j] *= scx;
    f32x4 acc[8]; mfma_core(av, prm.bhi + 7*2048, prm.blo + 7*2048, lane, acc);
    biasrelu(acc, prm.fco_b, l15, false);
    float ss4[4] = {0.f,0.f,0.f,0.f};
    #pragma unroll
    for (int ct = 0; ct < 8; ++ct)
      #pragma unroll
      for (int q = 0; q < 4; ++q)
        ss4[q] = fmaf(acc[ct][q], acc[ct][q], ss4[q]);
    #pragma unroll
    for (int q = 0; q < 4; ++q){
      ss4[q] = red16(ss4[q]);
      ss4[q] = 1.0f / fmaxf(sqrtf(ss4[q]), 1e-12f);
    }
    #pragma unroll
    for (int ct = 0; ct < 8; ++ct)
      #pragma unroll
      for (int q = 0; q < 4; ++q)
        prm.out[(rb + kg*4 + q)*HD + ct*16 + l15] = acc[ct][q]*ss4[q];
  }
}

extern "C" void kernel_launch(void* const* d_in, const int* in_sizes, int n_in,
                              void* d_out, int out_size, void* d_ws, size_t ws_size,
                              hipStream_t stream) {
  KParams prm;
  prm.x     = (const float*)d_in[0];
  prm.ei    = (const int*)  d_in[1];
  prm.fc0_w = (const float*)d_in[2];
  prm.fc0_b = (const float*)d_in[3];
  prm.w1    = (const float*)d_in[4];
  prm.b1    = (const float*)d_in[5];
  prm.gamma = (const float*)d_in[6];
  prm.beta  = (const float*)d_in[7];
  prm.w2    = (const float*)d_in[8];
  prm.b2    = (const float*)d_in[9];
  prm.fco_w = (const float*)d_in[10];
  prm.fco_b = (const float*)d_in[11];
  prm.p     = (const float*)d_in[12];
  prm.out   = (float*)d_out;

  float* ws = (float*)d_ws;
  prm.h    = ws;
  prm.zA   = prm.h  + (size_t)NN*HD;
  prm.zB   = prm.zA + (size_t)NN*HD;
  prm.t    = prm.zB + (size_t)NN*HD;
  prm.part = prm.t  + (size_t)NN*HD;              // [256*256]
  prm.bhi  = (bf16x8*)(prm.part + 256*256);       // [8*2048]
  prm.blo  = prm.bhi + 8*2048;
  prm.hb   = (unsigned short*)(prm.blo + 8*2048); // [NN*HD] bf16 mirror
  prm.cnt  = (int*)(prm.hb + (size_t)NN*HD);
  prm.ptr  = prm.cnt + NN;                        // [NN+1]
  prm.fil  = prm.ptr + NN + 1;                    // [NN]
  prm.eidx = (unsigned short*)(prm.fil + NN);     // [NE]
  prm.locpre = (int*)(prm.eidx + NE);             // [NSB*256]
  prm.btot = prm.locpre + NSB*256;                // [NSB]
  prm.boff = prm.btot + NSB;                      // [NSB]
  prm.scaling = tanhf(0.5f);

  void* args[] = { (void*)&prm };
  hipLaunchCooperativeKernel((void*)fused_k, dim3(NBLK), dim3(NTHR), args, 0, stream);
}

// Round 5
// 309.298 us; speedup vs baseline: 3.0461x; 3.0461x over previous
//
#include <hip/hip_runtime.h>
#include <math.h>

#define NN 40000
#define HD 128
#define NE 640000
#define MINN 1e-15f
#define NSB 157     // ceil(NN/256) scan chunks
#define GB  2500    // 16-row tiles, 1 wave each
#define HB_BLK 512  // hist blocks appended to fc0 dispatch

typedef __attribute__((ext_vector_type(8))) short bf16x8;
typedef __attribute__((ext_vector_type(4))) float f32x4;

__device__ __forceinline__ float red16(float v){
  v += __shfl_xor(v, 1, 64); v += __shfl_xor(v, 2, 64);
  v += __shfl_xor(v, 4, 64); v += __shfl_xor(v, 8, 64);
  return v;
}

__device__ __forceinline__ float bf2f(short h){
  return __uint_as_float(((unsigned)(unsigned short)h) << 16);
}
__device__ __forceinline__ short f2bf(float v){
  unsigned u = __float_as_uint(v);
  u += 0x7FFF + ((u >> 16) & 1);       // RNE
  return (short)(u >> 16);
}

// gather accumulate: 8 bf16 cols from one uint4 row-chunk
#define GACC(A,V) \
  A[0] += __uint_as_float((V).x << 16); A[1] += __uint_as_float((V).x & 0xffff0000u); \
  A[2] += __uint_as_float((V).y << 16); A[3] += __uint_as_float((V).y & 0xffff0000u); \
  A[4] += __uint_as_float((V).z << 16); A[5] += __uint_as_float((V).z & 0xffff0000u); \
  A[6] += __uint_as_float((V).w << 16); A[7] += __uint_as_float((V).w & 0xffff0000u);

// ---- A rows (rb+l15, cols ks*32+kg*8..+8) from global row-major [.,128] ----
__device__ __forceinline__ void loadA_g(const float* __restrict__ A, long rb,
                                        int l15, int kg, float av[4][8]){
  #pragma unroll
  for (int ks = 0; ks < 4; ++ks){
    const float* ap = A + (rb + l15)*HD + ks*32 + kg*8;
    float4 a0 = *(const float4*)ap;
    float4 a1 = *(const float4*)(ap + 4);
    av[ks][0]=a0.x; av[ks][1]=a0.y; av[ks][2]=a0.z; av[ks][3]=a0.w;
    av[ks][4]=a1.x; av[ks][5]=a1.y; av[ks][6]=a1.z; av[ks][7]=a1.w;
  }
}

// ---- split-bf16 3-term MFMA: acc = A(f32 via hi+lo) @ W^T ----
__device__ __forceinline__ void mfma_core(const float av[4][8],
    const bf16x8* __restrict__ bh, const bf16x8* __restrict__ bl,
    int lane, f32x4 acc[8]){
  #pragma unroll
  for (int ct = 0; ct < 8; ++ct){
    acc[ct][0]=0.f; acc[ct][1]=0.f; acc[ct][2]=0.f; acc[ct][3]=0.f;
  }
  #pragma unroll
  for (int ks = 0; ks < 4; ++ks){
    bf16x8 ah, al;
    #pragma unroll
    for (int j = 0; j < 8; ++j){
      float v = av[ks][j];
      short hh = f2bf(v);
      short ll = f2bf(v - bf2f(hh));
      ah[j] = hh; al[j] = ll;
    }
    #pragma unroll
    for (int ct = 0; ct < 8; ++ct){
      bf16x8 bhv = bh[(ks*8 + ct)*64 + lane];
      bf16x8 blv = bl[(ks*8 + ct)*64 + lane];
      acc[ct] = __builtin_amdgcn_mfma_f32_16x16x32_bf16(ah, bhv, acc[ct], 0, 0, 0);
      acc[ct] = __builtin_amdgcn_mfma_f32_16x16x32_bf16(al, bhv, acc[ct], 0, 0, 0);
      acc[ct] = __builtin_amdgcn_mfma_f32_16x16x32_bf16(ah, blv, acc[ct], 0, 0, 0);
    }
  }
}

__device__ __forceinline__ void biasrelu(f32x4 acc[8], const float* __restrict__ bias,
                                         int l15, bool relu){
  #pragma unroll
  for (int ct = 0; ct < 8; ++ct){
    float bb = bias[ct*16 + l15];
    #pragma unroll
    for (int q = 0; q < 4; ++q){
      float v = acc[ct][q] + bb;
      if (relu) v = fmaxf(v, 0.f);
      acc[ct][q] = v;
    }
  }
}

// ---------------- K1: weight prep (blocks 0..255) + zero cnt/part2 (blocks 256+) ----
__global__ __launch_bounds__(64) void zero_prep_k(const float* __restrict__ fc0_w,
    const float* __restrict__ w1, const float* __restrict__ w2,
    const float* __restrict__ fco_w, bf16x8* __restrict__ bhi,
    bf16x8* __restrict__ blo, int* __restrict__ cnt, float* __restrict__ part2){
  int bid = blockIdx.x;
  if (bid < 256){
    int gid = bid*64 + threadIdx.x;    // 0..16383
    int widx = gid >> 11;
    const float* W;
    if (widx == 0)      W = fc0_w;
    else if (widx <= 3) W = w1 + (size_t)(widx-1)*HD*HD;
    else if (widx <= 6) W = w2 + (size_t)(widx-4)*HD*HD;
    else                W = fco_w;
    int f  = gid & 2047;
    int ln = f & 63;
    int ct = (f >> 6) & 7;
    int ks = f >> 9;
    int n  = ct*16 + (ln & 15);
    int k0 = ks*32 + (ln >> 4)*8;
    bf16x8 hv, lv;
    #pragma unroll
    for (int j = 0; j < 8; ++j){
      float v = W[n*HD + k0 + j];
      short hh = f2bf(v);
      short ll = f2bf(v - bf2f(hh));
      hv[j] = hh; lv[j] = ll;
    }
    bhi[widx*2048 + f] = hv; blo[widx*2048 + f] = lv;
  } else {
    int i = (bid-256)*64 + threadIdx.x;
    const int st = 161*64;
    for (int j = i; j < NN; j += st) cnt[j] = 0;
    for (int j = i; j < 2048; j += st) part2[j] = 0.f;
  }
}

// ---------------- K2: fc0 tiles (blocks 0..2499) + edge histogram (blocks 2500+) ----
__global__ __launch_bounds__(64) void fc0hist_k(const float* __restrict__ x,
    const int* __restrict__ dst, int* __restrict__ cnt,
    const bf16x8* __restrict__ bhi, const bf16x8* __restrict__ blo,
    const float* __restrict__ fc0_b, float* __restrict__ h,
    unsigned short* __restrict__ hb, float* __restrict__ zB, float scaling){
  int bid = blockIdx.x;
  if (bid >= GB){
    int i = (bid - GB)*64 + threadIdx.x;
    const int st = HB_BLK*64;
    for (; i < NE; i += st) atomicAdd(&cnt[dst[i]], 1);
    return;
  }
  const int lane = threadIdx.x;
  const int l15 = lane & 15, kg = lane >> 4;
  const long rb = (long)bid*16;
  float av[4][8]; loadA_g(x, rb, l15, kg, av);
  f32x4 acc[8]; mfma_core(av, bhi, blo, lane, acc);
  biasrelu(acc, fc0_b, l15, true);
  #pragma unroll
  for (int ct = 0; ct < 8; ++ct)
    #pragma unroll
    for (int q = 0; q < 4; ++q){
      float v = acc[ct][q];
      long row = rb + kg*4 + q;
      h[row*HD + ct*16 + l15] = v;
      hb[row*HD + ct*16 + l15] = (unsigned short)f2bf(v);
    }
  #pragma unroll
  for (int q = 0; q < 4; ++q){
    float ss = 0.f;
    #pragma unroll
    for (int ct = 0; ct < 8; ++ct) ss = fmaf(acc[ct][q], acc[ct][q], ss);
    ss = red16(ss);
    float sc2 = scaling / sqrtf(ss);
    long row = rb + kg*4 + q;
    #pragma unroll
    for (int ct = 0; ct < 8; ++ct)
      zB[row*HD + ct*16 + l15] = acc[ct][q]*sc2;
  }
}

// ---------------- K3: per-chunk inclusive scan ----------------
__global__ __launch_bounds__(256) void scan1_k(const int* __restrict__ cnt,
    int* __restrict__ locpre, int* __restrict__ btot){
  __shared__ int s[256];
  int t = threadIdx.x;
  int idx = blockIdx.x*256 + t;
  int v = (idx < NN) ? cnt[idx] : 0;
  s[t] = v; __syncthreads();
  for (int off = 1; off < 256; off <<= 1){
    int x = (t >= off) ? s[t-off] : 0;
    __syncthreads(); s[t] += x; __syncthreads();
  }
  locpre[idx] = s[t] - v;
  if (t == 255) btot[blockIdx.x] = s[255];
}

// ---------------- K4: merged scan2+scan3 (each block redundantly scans btot) ----
__global__ __launch_bounds__(256) void scan23_k(const int* __restrict__ btot,
    const int* __restrict__ locpre, int* __restrict__ ptr, int* __restrict__ fil){
  __shared__ int s[256];
  int t = threadIdx.x;
  int v = (t < NSB) ? btot[t] : 0;
  s[t] = v; __syncthreads();
  for (int off = 1; off < 256; off <<= 1){
    int x = (t >= off) ? s[t-off] : 0;
    __syncthreads(); s[t] += x; __syncthreads();
  }
  int bid = blockIdx.x;
  int pre = (bid == 0) ? 0 : s[bid-1];
  int idx = bid*256 + t;
  if (idx < NN){
    int v2 = pre + locpre[idx];
    ptr[idx] = v2; fil[idx] = v2;
  }
  if (bid == 0 && t == 0) ptr[NN] = s[NSB-1];
}

// ---------------- K5: fill edge buckets ----------------
__global__ void fill_k(const int* __restrict__ src, const int* __restrict__ dst,
    int* __restrict__ fill, unsigned short* __restrict__ eidx, int ne){
  int i = blockIdx.x*blockDim.x + threadIdx.x;
  int st = gridDim.x*blockDim.x;
  for (; i < ne; i += st){
    int d = dst[i];
    int pos = atomicAdd(&fill[d], 1);
    eidx[pos] = (unsigned short)src[i];
  }
}

// ---------------- MFMA GEMM with fused pre/post ops (R1 structure, 1 wave/block) ----
// STATS: atomic accumulation into part2[8][256] (replaces part[2500][256]+red1).
// ZSTEP: zc/zp/p loads hoisted BEFORE the MFMA stream (latency overlap).
template<bool GATHER, bool RELU, bool BN_IN, bool XH_IN, bool NORM_OUT,
         bool STATS, bool WRITE_HB, bool ZINIT, bool WRITE_OUT,
         bool ZSTEP, bool ZFIRST>
__global__ __launch_bounds__(64) void mgemm_k(const float* __restrict__ A,
    const bf16x8* __restrict__ bhi, const bf16x8* __restrict__ blo,
    const float* __restrict__ bias, const float* __restrict__ scale,
    const float* __restrict__ shift, float* __restrict__ out,
    unsigned short* __restrict__ hbout, float* __restrict__ part2,
    float* __restrict__ zout, float scaling,
    const float* __restrict__ zpin, const float* __restrict__ zcin,
    const float* __restrict__ pvec,
    const uint4* __restrict__ hb4, const int* __restrict__ gptr,
    const unsigned short* __restrict__ eidx)
{
  const int lane = threadIdx.x;
  const int l15 = lane & 15, kg = lane >> 4;
  const long rb = (long)blockIdx.x*16;   // 2500*16 = 40000 exact

  // ---- A rows into av[ks][j]: row rb+l15, cols ks*32+kg*8 .. +8 ----
  float av[4][8];
  if constexpr (GATHER){
    // per-wave LDS tile, 132-dw padded rows (bank-benign)
    __shared__ float tl[16*132];
    const int grp = kg, l = l15;         // 4 groups x 16 lanes; 4 nodes/group
    #pragma unroll
    for (int s = 0; s < 4; ++s){
      const int r = grp*4 + s;
      const long node = rb + r;
      int beg = gptr[node], end = gptr[node+1];
      const float4* selfp = (const float4*)(A + node*HD) + l*2;
      float4 s0 = selfp[0], s1 = selfp[1];
      float ga[8] = {s0.x,s0.y,s0.z,s0.w,s1.x,s1.y,s1.z,s1.w};
      int e = beg;
      for (; e + 8 <= end; e += 8){
        int i0 = eidx[e],   i1 = eidx[e+1], i2 = eidx[e+2], i3 = eidx[e+3];
        int i4 = eidx[e+4], i5 = eidx[e+5], i6 = eidx[e+6], i7 = eidx[e+7];
        uint4 v0 = hb4[(long)i0*16 + l];
        uint4 v1 = hb4[(long)i1*16 + l];
        uint4 v2 = hb4[(long)i2*16 + l];
        uint4 v3 = hb4[(long)i3*16 + l];
        uint4 v4 = hb4[(long)i4*16 + l];
        uint4 v5 = hb4[(long)i5*16 + l];
        uint4 v6 = hb4[(long)i6*16 + l];
        uint4 v7 = hb4[(long)i7*16 + l];
        GACC(ga,v0) GACC(ga,v1) GACC(ga,v2) GACC(ga,v3)
        GACC(ga,v4) GACC(ga,v5) GACC(ga,v6) GACC(ga,v7)
      }
      if (e + 4 <= end){
        int i0 = eidx[e], i1 = eidx[e+1], i2 = eidx[e+2], i3 = eidx[e+3];
        uint4 v0 = hb4[(long)i0*16 + l];
        uint4 v1 = hb4[(long)i1*16 + l];
        uint4 v2 = hb4[(long)i2*16 + l];
        uint4 v3 = hb4[(long)i3*16 + l];
        GACC(ga,v0) GACC(ga,v1) GACC(ga,v2) GACC(ga,v3)
        e += 4;
      }
      for (; e < end; ++e){
        uint4 v = hb4[(long)eidx[e]*16 + l];
        GACC(ga,v)
      }
      float4* tp = (float4*)(tl + r*132 + l*8);
      float4 o0 = {ga[0],ga[1],ga[2],ga[3]};
      float4 o1 = {ga[4],ga[5],ga[6],ga[7]};
      tp[0] = o0; tp[1] = o1;
    }
    #pragma unroll
    for (int ks = 0; ks < 4; ++ks){
      const float* ap = tl + l15*132 + ks*32 + kg*8;
      float4 a0 = *(const float4*)ap;
      float4 a1 = *(const float4*)(ap + 4);
      av[ks][0]=a0.x; av[ks][1]=a0.y; av[ks][2]=a0.z; av[ks][3]=a0.w;
      av[ks][4]=a1.x; av[ks][5]=a1.y; av[ks][6]=a1.z; av[ks][7]=a1.w;
    }
  } else {
    loadA_g(A, rb, l15, kg, av);
  }

  // ---- ZSTEP operand prefetch (issued before the MFMA stream; consumed after) ----
  float zc_a[4][8], zp_a[4][8], pvr[8];
  if constexpr (ZSTEP){
    #pragma unroll
    for (int q = 0; q < 4; ++q){
      const long row = rb + kg*4 + q;
      #pragma unroll
      for (int ct = 0; ct < 8; ++ct)
        zc_a[q][ct] = zcin[row*HD + ct*16 + l15];
    }
    if constexpr (!ZFIRST){
      #pragma unroll
      for (int q = 0; q < 4; ++q){
        const long row = rb + kg*4 + q;
        #pragma unroll
        for (int ct = 0; ct < 8; ++ct)
          zp_a[q][ct] = zpin[row*HD + ct*16 + l15];
      }
    }
    #pragma unroll
    for (int ct = 0; ct < 8; ++ct) pvr[ct] = pvec[ct*16 + l15];
  }

  if (BN_IN){
    #pragma unroll
    for (int ks = 0; ks < 4; ++ks){
      const int k0 = ks*32 + kg*8;
      float4 s0 = *(const float4*)(scale + k0);
      float4 s1 = *(const float4*)(scale + k0 + 4);
      float4 h0 = *(const float4*)(shift + k0);
      float4 h1 = *(const float4*)(shift + k0 + 4);
      float sc[8] = {s0.x,s0.y,s0.z,s0.w,s1.x,s1.y,s1.z,s1.w};
      float sh[8] = {h0.x,h0.y,h0.z,h0.w,h1.x,h1.y,h1.z,h1.w};
      #pragma unroll
      for (int j = 0; j < 8; ++j)
        av[ks][j] = fmaf(av[ks][j], sc[j], sh[j]);
    }
  }
  if (XH_IN){
    float ss = 0.f;
    #pragma unroll
    for (int ks = 0; ks < 4; ++ks)
      #pragma unroll
      for (int j = 0; j < 8; ++j)
        ss = fmaf(av[ks][j], av[ks][j], ss);
    ss += __shfl_xor(ss, 16, 64);
    ss += __shfl_xor(ss, 32, 64);
    float n = sqrtf(ss);
    float yn = fmaxf(n, MINN);
    float c = fminf(yn, 1.0f);
    float at = 0.5f*logf((1.0f + c)/(1.0f - c));
    float scx = at / yn;
    #pragma unroll
    for (int ks = 0; ks < 4; ++ks)
      #pragma unroll
      for (int j = 0; j < 8; ++j)
        av[ks][j] *= scx;
  }

  f32x4 acc[8];
  mfma_core(av, bhi, blo, lane, acc);
  biasrelu(acc, bias, l15, RELU);

  if (NORM_OUT){
    float ss[4] = {0.f,0.f,0.f,0.f};
    #pragma unroll
    for (int ct = 0; ct < 8; ++ct)
      #pragma unroll
      for (int q = 0; q < 4; ++q)
        ss[q] = fmaf(acc[ct][q], acc[ct][q], ss[q]);
    #pragma unroll
    for (int q = 0; q < 4; ++q){
      #pragma unroll
      for (int m = 1; m < 16; m <<= 1) ss[q] += __shfl_xor(ss[q], m, 64);
      ss[q] = 1.0f / fmaxf(sqrtf(ss[q]), 1e-12f);
    }
    #pragma unroll
    for (int ct = 0; ct < 8; ++ct)
      #pragma unroll
      for (int q = 0; q < 4; ++q)
        acc[ct][q] *= ss[q];
  }

  if (STATS){
    #pragma unroll
    for (int ct = 0; ct < 8; ++ct){
      float s = 0.f, q2 = 0.f;
      #pragma unroll
      for (int q = 0; q < 4; ++q){
        float v = acc[ct][q];
        s += v; q2 = fmaf(v, v, q2);
      }
      s  += __shfl_xor(s, 16, 64);  s  += __shfl_xor(s, 32, 64);
      q2 += __shfl_xor(q2, 16, 64); q2 += __shfl_xor(q2, 32, 64);
      if (kg == 0){
        const int slot = (blockIdx.x & 7)*256;
        atomicAdd(&part2[slot + ct*16 + l15], s);
        atomicAdd(&part2[slot + 128 + ct*16 + l15], q2);
      }
    }
  }

  if (ZINIT){
    #pragma unroll
    for (int q = 0; q < 4; ++q){
      float ss = 0.f;
      #pragma unroll
      for (int ct = 0; ct < 8; ++ct)
        ss = fmaf(acc[ct][q], acc[ct][q], ss);
      ss = red16(ss);
      float sc2 = scaling / sqrtf(ss);
      long row = rb + kg*4 + q;
      #pragma unroll
      for (int ct = 0; ct < 8; ++ct)
        zout[row*HD + ct*16 + l15] = acc[ct][q]*sc2;
    }
  }

  if constexpr (ZSTEP){
    // q_ = p/|p| is row-independent
    float pq = 0.f;
    #pragma unroll
    for (int ct = 0; ct < 8; ++ct) pq = fmaf(pvr[ct], pvr[ct], pq);
    pq = red16(pq);
    float qi = 1.0f / fmaxf(sqrtf(pq), MINN);
    #pragma unroll
    for (int ct = 0; ct < 8; ++ct) pvr[ct] *= qi;

    #pragma unroll
    for (int q = 0; q < 4; ++q){
      const long row = rb + kg*4 + q;
      float zc[8], zp[8];
      #pragma unroll
      for (int ct = 0; ct < 8; ++ct) zc[ct] = zc_a[q][ct];
      if constexpr (!ZFIRST){
        #pragma unroll
        for (int ct = 0; ct < 8; ++ct) zp[ct] = zp_a[q][ct];
      } else {
        #pragma unroll
        for (int ct = 0; ct < 8; ++ct) zp[ct] = 0.f;
      }
      float hh = 0.f, cc = 0.f;
      #pragma unroll
      for (int ct = 0; ct < 8; ++ct){
        hh = fmaf(acc[ct][q], acc[ct][q], hh);
        cc = fmaf(zc[ct], zc[ct], cc);
      }
      hh = red16(hh); cc = red16(cc);
      float zs = scaling / sqrtf(hh);
      float di = 1.0f / fmaxf(cc, MINN);
      float r2 = cc*di*di - 1.0f;
      float a[8], u[8]; float uu = 0.f;
      #pragma unroll
      for (int ct = 0; ct < 8; ++ct){
        a[ct] = zc[ct]*di;
        u[ct] = zp[ct] - a[ct];
        uu = fmaf(u[ct], u[ct], uu);
      }
      uu = red16(uu);
      float f = r2 / fmaxf(uu, MINN);
      float zpar[8]; float pn2 = 0.f;
      #pragma unroll
      for (int ct = 0; ct < 8; ++ct){
        zpar[ct] = fmaf(f, u[ct], a[ct]);
        pn2 = fmaf(zpar[ct], zpar[ct], pn2);
      }
      pn2 = red16(pn2);
      float pinv = 1.0f / fmaxf(sqrtf(pn2), MINN);
      float rv[8], zch[8]; float rz = 0.f, rr = 0.f;
      #pragma unroll
      for (int ct = 0; ct < 8; ++ct){
        zch[ct] = acc[ct][q]*zs;
        rv[ct] = pvr[ct] - zpar[ct]*pinv;
        rz = fmaf(rv[ct], zch[ct], rz);
        rr = fmaf(rv[ct], rv[ct], rr);
      }
      rz = red16(rz); rr = red16(rr);
      float mm = rz / rr;
      float u2[8]; float uu2 = 0.f;
      #pragma unroll
      for (int ct = 0; ct < 8; ++ct){
        float z2 = fmaf(-2.0f*mm, rv[ct], zch[ct]);
        u2[ct] = z2 - a[ct];
        uu2 = fmaf(u2[ct], u2[ct], uu2);
      }
      uu2 = red16(uu2);
      float f2 = r2 / fmaxf(uu2, MINN);
      #pragma unroll
      for (int ct = 0; ct < 8; ++ct)
        zout[row*HD + ct*16 + l15] = fmaf(f2, u2[ct], a[ct]);
    }
  }

  if constexpr (WRITE_OUT || WRITE_HB){
    #pragma unroll
    for (int ct = 0; ct < 8; ++ct)
      #pragma unroll
      for (int q = 0; q < 4; ++q){
        float v = acc[ct][q];
        long row = rb + kg*4 + q;
        if (WRITE_OUT) out[row*HD + ct*16 + l15] = v;
        if (WRITE_HB) hbout[row*HD + ct*16 + l15] = (unsigned short)f2bf(v);
      }
  }
}

// ---------------- BN finalize: part2[8][256] -> scale/shift; re-zero part2 ----------
__global__ __launch_bounds__(256) void bnfin_k(float* __restrict__ part2,
    const float* __restrict__ g, const float* __restrict__ b,
    float* __restrict__ scale, float* __restrict__ shift){
  __shared__ float sm[256];
  float tot = 0.f;
  #pragma unroll
  for (int r = 0; r < 8; ++r) tot += part2[r*256 + threadIdx.x];
  sm[threadIdx.x] = tot;
  __syncthreads();
  if (threadIdx.x < 128){
    int c = threadIdx.x;
    float s = sm[c], q = sm[c + 128];
    float mu  = s * (1.0f/NN);
    float var = q * (1.0f/NN) - mu*mu;
    float istd = rsqrtf(var + 1e-5f);
    float scv = g[c]*istd;
    scale[c] = scv;
    shift[c] = fmaf(-mu, scv, b[c]);
  }
  #pragma unroll
  for (int r = 0; r < 8; ++r) part2[r*256 + threadIdx.x] = 0.f;
}

extern "C" void kernel_launch(void* const* d_in, const int* in_sizes, int n_in,
                              void* d_out, int out_size, void* d_ws, size_t ws_size,
                              hipStream_t stream) {
  const float* x       = (const float*)d_in[0];
  const int*   ei      = (const int*)  d_in[1];
  const float* fc0_w   = (const float*)d_in[2];
  const float* fc0_b   = (const float*)d_in[3];
  const float* w1      = (const float*)d_in[4];
  const float* b1      = (const float*)d_in[5];
  const float* gamma   = (const float*)d_in[6];
  const float* beta    = (const float*)d_in[7];
  const float* w2      = (const float*)d_in[8];
  const float* b2      = (const float*)d_in[9];
  const float* fco_w   = (const float*)d_in[10];
  const float* fco_b   = (const float*)d_in[11];
  const float* p       = (const float*)d_in[12];

  float* out = (float*)d_out;
  float* ws  = (float*)d_ws;

  float* h     = ws;                     // [NN*HD] f32
  float* zA    = h   + (size_t)NN*HD;
  float* zB    = zA  + (size_t)NN*HD;
  float* part2 = zB  + (size_t)NN*HD;    // [8*256]
  float* scale = part2 + 8*256;          // [128]
  float* shift = scale + 128;            // [128]
  bf16x8* bhi  = (bf16x8*)(shift + 128); // [8*2048]
  bf16x8* blo  = bhi + 8*2048;           // [8*2048]
  unsigned short* hb = (unsigned short*)(blo + 8*2048); // [NN*HD] bf16 mirror
  int* cnt     = (int*)(hb + (size_t)NN*HD);
  int* ptr     = cnt + NN;               // [NN+1]
  int* fil     = ptr + NN + 1;           // [NN]
  unsigned short* eidx = (unsigned short*)(fil + NN);   // [NE] (u16 src ids)
  int* locpre  = (int*)(eidx + NE);      // [NSB*256]
  int* btot    = locpre + NSB*256;       // [NSB]
  float* t = out;                        // reuse d_out as the w1-activation buffer

  const int* src = ei;
  const int* dst = ei + NE;
  const float scaling = tanhf(0.5f);

  // K1: weight prep + zero cnt/part2
  zero_prep_k<<<417, 64, 0, stream>>>(fc0_w, w1, w2, fco_w, bhi, blo, cnt, part2);

  // K2: fc0 tiles (h, hb, zinit->zB) + edge histogram
  fc0hist_k<<<GB + HB_BLK, 64, 0, stream>>>(x, dst, cnt, bhi, blo, fc0_b,
                                            h, hb, zB, scaling);

  // K3-K5: scan + fill (CSR by dst)
  scan1_k<<<NSB, 256, 0, stream>>>(cnt, locpre, btot);
  scan23_k<<<NSB, 256, 0, stream>>>(btot, locpre, ptr, fil);
  fill_k<<<512, 256, 0, stream>>>(src, dst, fil, eidx, NE);

  float* zprev = zA; float* zcur = zB;

  for (int i = 0; i < 3; ++i) {
    // t = relu((h + agg(h)) @ w1^T + b1); stats -> atomic part2[8][256]
    mgemm_k<true,true,false,false,false,true,false,false,true,false,false>
        <<<GB, 64, 0, stream>>>(
        h, bhi + (1+i)*2048, blo + (1+i)*2048, b1 + i*HD, nullptr, nullptr, t,
        nullptr, part2, nullptr, 0.f, nullptr, nullptr, nullptr,
        (const uint4*)hb, ptr, eidx);
    bnfin_k<<<1, 256, 0, stream>>>(part2, gamma + i*HD, beta + i*HD, scale, shift);
    // h = relu( BN(t) @ w2^T + b2 ) + fused hyperbolic z-step (hoisted z loads).
    if (i == 0)
      mgemm_k<false,true,true,false,false,false,true,false,true,true,true>
          <<<GB, 64, 0, stream>>>(
          t, bhi + 4*2048, blo + 4*2048, b2, scale, shift, h, hb, nullptr,
          zprev, scaling, zprev, zcur, p, nullptr, nullptr, nullptr);
    else if (i == 1)
      mgemm_k<false,true,true,false,false,false,true,false,true,true,false>
          <<<GB, 64, 0, stream>>>(
          t, bhi + 5*2048, blo + 5*2048, b2 + HD, scale, shift, h, hb, nullptr,
          zprev, scaling, zprev, zcur, p, nullptr, nullptr, nullptr);
    else
      mgemm_k<false,true,true,false,false,false,false,false,false,true,false>
          <<<GB, 64, 0, stream>>>(
          t, bhi + 6*2048, blo + 6*2048, b2 + 2*HD, scale, shift, h, nullptr, nullptr,
          zprev, scaling, zprev, zcur, p, nullptr, nullptr, nullptr);
    float* tmp = zprev; zprev = zcur; zcur = tmp;
  }

  // out = normalize( logmap0(z_cur) @ fc_out^T + fc_out_b )
  mgemm_k<false,false,false,true,true,false,false,false,true,false,false>
      <<<GB, 64, 0, stream>>>(
      zcur, bhi + 7*2048, blo + 7*2048, fco_b, nullptr, nullptr, out,
      nullptr, nullptr, nullptr, 0.f, nullptr, nullptr, nullptr,
      nullptr, nullptr, nullptr);
}

// Round 6
// 293.617 us; speedup vs baseline: 3.2088x; 1.0534x over previous
//
#include <hip/hip_runtime.h>
#include <math.h>

#define NN 40000
#define HD 128
#define NE 640000
#define MINN 1e-15f
#define NSB 157     // ceil(NN/256) scan chunks
#define GB  2500    // 16-row tiles
#define HB_BLK 512  // hist blocks appended to fc0 dispatch

typedef __attribute__((ext_vector_type(8))) short bf16x8;
typedef __attribute__((ext_vector_type(4))) float f32x4;

__device__ __forceinline__ float red16(float v){
  v += __shfl_xor(v, 1, 64); v += __shfl_xor(v, 2, 64);
  v += __shfl_xor(v, 4, 64); v += __shfl_xor(v, 8, 64);
  return v;
}

__device__ __forceinline__ float bf2f(short h){
  return __uint_as_float(((unsigned)(unsigned short)h) << 16);
}
__device__ __forceinline__ short f2bf(float v){
  unsigned u = __float_as_uint(v);
  u += 0x7FFF + ((u >> 16) & 1);       // RNE
  return (short)(u >> 16);
}

// gather accumulate: 8 bf16 cols from one uint4 row-chunk
#define GACC(A,V) \
  A[0] += __uint_as_float((V).x << 16); A[1] += __uint_as_float((V).x & 0xffff0000u); \
  A[2] += __uint_as_float((V).y << 16); A[3] += __uint_as_float((V).y & 0xffff0000u); \
  A[4] += __uint_as_float((V).z << 16); A[5] += __uint_as_float((V).z & 0xffff0000u); \
  A[6] += __uint_as_float((V).w << 16); A[7] += __uint_as_float((V).w & 0xffff0000u);

// ---- A rows (rb+l15, cols ks*32+kg*8..+8) from global row-major [.,128] ----
__device__ __forceinline__ void loadA_g(const float* __restrict__ A, long rb,
                                        int l15, int kg, float av[4][8]){
  #pragma unroll
  for (int ks = 0; ks < 4; ++ks){
    const float* ap = A + (rb + l15)*HD + ks*32 + kg*8;
    float4 a0 = *(const float4*)ap;
    float4 a1 = *(const float4*)(ap + 4);
    av[ks][0]=a0.x; av[ks][1]=a0.y; av[ks][2]=a0.z; av[ks][3]=a0.w;
    av[ks][4]=a1.x; av[ks][5]=a1.y; av[ks][6]=a1.z; av[ks][7]=a1.w;
  }
}

// ---- split-bf16 3-term MFMA: acc = A(f32 via hi+lo) @ W^T ----
__device__ __forceinline__ void mfma_core(const float av[4][8],
    const bf16x8* __restrict__ bh, const bf16x8* __restrict__ bl,
    int lane, f32x4 acc[8]){
  #pragma unroll
  for (int ct = 0; ct < 8; ++ct){
    acc[ct][0]=0.f; acc[ct][1]=0.f; acc[ct][2]=0.f; acc[ct][3]=0.f;
  }
  #pragma unroll
  for (int ks = 0; ks < 4; ++ks){
    bf16x8 ah, al;
    #pragma unroll
    for (int j = 0; j < 8; ++j){
      float v = av[ks][j];
      short hh = f2bf(v);
      short ll = f2bf(v - bf2f(hh));
      ah[j] = hh; al[j] = ll;
    }
    #pragma unroll
    for (int ct = 0; ct < 8; ++ct){
      bf16x8 bhv = bh[(ks*8 + ct)*64 + lane];
      bf16x8 blv = bl[(ks*8 + ct)*64 + lane];
      acc[ct] = __builtin_amdgcn_mfma_f32_16x16x32_bf16(ah, bhv, acc[ct], 0, 0, 0);
      acc[ct] = __builtin_amdgcn_mfma_f32_16x16x32_bf16(al, bhv, acc[ct], 0, 0, 0);
      acc[ct] = __builtin_amdgcn_mfma_f32_16x16x32_bf16(ah, blv, acc[ct], 0, 0, 0);
    }
  }
}

__device__ __forceinline__ void biasrelu(f32x4 acc[8], const float* __restrict__ bias,
                                         int l15, bool relu){
  #pragma unroll
  for (int ct = 0; ct < 8; ++ct){
    float bb = bias[ct*16 + l15];
    #pragma unroll
    for (int q = 0; q < 4; ++q){
      float v = acc[ct][q] + bb;
      if (relu) v = fmaxf(v, 0.f);
      acc[ct][q] = v;
    }
  }
}

// ---------------- K1: weight prep (blocks 0..255) + zero cnt/part2 (blocks 256+) ----
__global__ __launch_bounds__(64) void zero_prep_k(const float* __restrict__ fc0_w,
    const float* __restrict__ w1, const float* __restrict__ w2,
    const float* __restrict__ fco_w, bf16x8* __restrict__ bhi,
    bf16x8* __restrict__ blo, int* __restrict__ cnt, float* __restrict__ part2){
  int bid = blockIdx.x;
  if (bid < 256){
    int gid = bid*64 + threadIdx.x;    // 0..16383
    int widx = gid >> 11;
    const float* W;
    if (widx == 0)      W = fc0_w;
    else if (widx <= 3) W = w1 + (size_t)(widx-1)*HD*HD;
    else if (widx <= 6) W = w2 + (size_t)(widx-4)*HD*HD;
    else                W = fco_w;
    int f  = gid & 2047;
    int ln = f & 63;
    int ct = (f >> 6) & 7;
    int ks = f >> 9;
    int n  = ct*16 + (ln & 15);
    int k0 = ks*32 + (ln >> 4)*8;
    bf16x8 hv, lv;
    #pragma unroll
    for (int j = 0; j < 8; ++j){
      float v = W[n*HD + k0 + j];
      short hh = f2bf(v);
      short ll = f2bf(v - bf2f(hh));
      hv[j] = hh; lv[j] = ll;
    }
    bhi[widx*2048 + f] = hv; blo[widx*2048 + f] = lv;
  } else {
    int i = (bid-256)*64 + threadIdx.x;
    const int st = 161*64;
    for (int j = i; j < NN; j += st) cnt[j] = 0;
    for (int j = i; j < 2048; j += st) part2[j] = 0.f;
  }
}

// ---------------- K2: fc0 tiles (blocks 0..2499) + edge histogram (blocks 2500+) ----
__global__ __launch_bounds__(64) void fc0hist_k(const float* __restrict__ x,
    const int* __restrict__ dst, int* __restrict__ cnt,
    const bf16x8* __restrict__ bhi, const bf16x8* __restrict__ blo,
    const float* __restrict__ fc0_b, float* __restrict__ h,
    unsigned short* __restrict__ hb, float* __restrict__ zB, float scaling){
  int bid = blockIdx.x;
  if (bid >= GB){
    int i = (bid - GB)*64 + threadIdx.x;
    const int st = HB_BLK*64;
    for (; i < NE; i += st) atomicAdd(&cnt[dst[i]], 1);
    return;
  }
  const int lane = threadIdx.x;
  const int l15 = lane & 15, kg = lane >> 4;
  const long rb = (long)bid*16;
  float av[4][8]; loadA_g(x, rb, l15, kg, av);
  f32x4 acc[8]; mfma_core(av, bhi, blo, lane, acc);
  biasrelu(acc, fc0_b, l15, true);
  #pragma unroll
  for (int ct = 0; ct < 8; ++ct)
    #pragma unroll
    for (int q = 0; q < 4; ++q){
      float v = acc[ct][q];
      long row = rb + kg*4 + q;
      h[row*HD + ct*16 + l15] = v;
      hb[row*HD + ct*16 + l15] = (unsigned short)f2bf(v);
    }
  #pragma unroll
  for (int q = 0; q < 4; ++q){
    float ss = 0.f;
    #pragma unroll
    for (int ct = 0; ct < 8; ++ct) ss = fmaf(acc[ct][q], acc[ct][q], ss);
    ss = red16(ss);
    float sc2 = scaling / sqrtf(ss);
    long row = rb + kg*4 + q;
    #pragma unroll
    for (int ct = 0; ct < 8; ++ct)
      zB[row*HD + ct*16 + l15] = acc[ct][q]*sc2;
  }
}

// ---------------- K3: per-chunk inclusive scan ----------------
__global__ __launch_bounds__(256) void scan1_k(const int* __restrict__ cnt,
    int* __restrict__ locpre, int* __restrict__ btot){
  __shared__ int s[256];
  int t = threadIdx.x;
  int idx = blockIdx.x*256 + t;
  int v = (idx < NN) ? cnt[idx] : 0;
  s[t] = v; __syncthreads();
  for (int off = 1; off < 256; off <<= 1){
    int x = (t >= off) ? s[t-off] : 0;
    __syncthreads(); s[t] += x; __syncthreads();
  }
  locpre[idx] = s[t] - v;
  if (t == 255) btot[blockIdx.x] = s[255];
}

// ---------------- K4: merged scan2+scan3 (each block redundantly scans btot) ----
__global__ __launch_bounds__(256) void scan23_k(const int* __restrict__ btot,
    const int* __restrict__ locpre, int* __restrict__ ptr, int* __restrict__ fil){
  __shared__ int s[256];
  int t = threadIdx.x;
  int v = (t < NSB) ? btot[t] : 0;
  s[t] = v; __syncthreads();
  for (int off = 1; off < 256; off <<= 1){
    int x = (t >= off) ? s[t-off] : 0;
    __syncthreads(); s[t] += x; __syncthreads();
  }
  int bid = blockIdx.x;
  int pre = (bid == 0) ? 0 : s[bid-1];
  int idx = bid*256 + t;
  if (idx < NN){
    int v2 = pre + locpre[idx];
    ptr[idx] = v2; fil[idx] = v2;
  }
  if (bid == 0 && t == 0) ptr[NN] = s[NSB-1];
}

// ---------------- K5: fill edge buckets ----------------
__global__ void fill_k(const int* __restrict__ src, const int* __restrict__ dst,
    int* __restrict__ fill, unsigned short* __restrict__ eidx, int ne){
  int i = blockIdx.x*blockDim.x + threadIdx.x;
  int st = gridDim.x*blockDim.x;
  for (; i < ne; i += st){
    int d = dst[i];
    int pos = atomicAdd(&fill[d], 1);
    eidx[pos] = (unsigned short)src[i];
  }
}

// ---------------- K6: gather + w1 GEMM, 4 waves/WG ----------------
// Waves 0-3: each of the 16 lane-groups gathers ONE node (serial chain = deg/8
// rounds instead of 4*deg/8) into the shared 16x132 LDS tile. After the barrier
// wave 0 alone runs the proven 16x128 GEMM + bias/relu + atomic stats + t-write.
__global__ __launch_bounds__(256) void gw1_k(const float* __restrict__ h,
    const bf16x8* __restrict__ bhi, const bf16x8* __restrict__ blo,
    const float* __restrict__ bias, float* __restrict__ t,
    float* __restrict__ part2, const uint4* __restrict__ hb4,
    const int* __restrict__ gptr, const unsigned short* __restrict__ eidx)
{
  __shared__ float tl[16*132];
  const int tid = threadIdx.x;
  const int lane = tid & 63;
  const int wv = tid >> 6;
  const int l15 = lane & 15, kg = lane >> 4;
  const long rb = (long)blockIdx.x*16;

  // ---- gather: lane-group (wv,kg) owns tile row r = wv*4+kg ----
  {
    const int r = wv*4 + kg;
    const long node = rb + r;
    int beg = gptr[node], end = gptr[node+1];
    const float4* selfp = (const float4*)(h + node*HD) + l15*2;
    float4 s0 = selfp[0], s1 = selfp[1];
    float ga[8] = {s0.x,s0.y,s0.z,s0.w,s1.x,s1.y,s1.z,s1.w};
    int e = beg;
    for (; e + 8 <= end; e += 8){
      int i0 = eidx[e],   i1 = eidx[e+1], i2 = eidx[e+2], i3 = eidx[e+3];
      int i4 = eidx[e+4], i5 = eidx[e+5], i6 = eidx[e+6], i7 = eidx[e+7];
      uint4 v0 = hb4[(long)i0*16 + l15];
      uint4 v1 = hb4[(long)i1*16 + l15];
      uint4 v2 = hb4[(long)i2*16 + l15];
      uint4 v3 = hb4[(long)i3*16 + l15];
      uint4 v4 = hb4[(long)i4*16 + l15];
      uint4 v5 = hb4[(long)i5*16 + l15];
      uint4 v6 = hb4[(long)i6*16 + l15];
      uint4 v7 = hb4[(long)i7*16 + l15];
      GACC(ga,v0) GACC(ga,v1) GACC(ga,v2) GACC(ga,v3)
      GACC(ga,v4) GACC(ga,v5) GACC(ga,v6) GACC(ga,v7)
    }
    if (e + 4 <= end){
      int i0 = eidx[e], i1 = eidx[e+1], i2 = eidx[e+2], i3 = eidx[e+3];
      uint4 v0 = hb4[(long)i0*16 + l15];
      uint4 v1 = hb4[(long)i1*16 + l15];
      uint4 v2 = hb4[(long)i2*16 + l15];
      uint4 v3 = hb4[(long)i3*16 + l15];
      GACC(ga,v0) GACC(ga,v1) GACC(ga,v2) GACC(ga,v3)
      e += 4;
    }
    for (; e < end; ++e){
      uint4 v = hb4[(long)eidx[e]*16 + l15];
      GACC(ga,v)
    }
    float4* tp = (float4*)(tl + r*132 + l15*8);
    float4 o0 = {ga[0],ga[1],ga[2],ga[3]};
    float4 o1 = {ga[4],ga[5],ga[6],ga[7]};
    tp[0] = o0; tp[1] = o1;
  }
  __syncthreads();
  if (wv != 0) return;

  // ---- wave 0: GEMM + bias/relu + stats + t-write (verbatim R5 math) ----
  float av[4][8];
  #pragma unroll
  for (int ks = 0; ks < 4; ++ks){
    const float* ap = tl + l15*132 + ks*32 + kg*8;
    float4 a0 = *(const float4*)ap;
    float4 a1 = *(const float4*)(ap + 4);
    av[ks][0]=a0.x; av[ks][1]=a0.y; av[ks][2]=a0.z; av[ks][3]=a0.w;
    av[ks][4]=a1.x; av[ks][5]=a1.y; av[ks][6]=a1.z; av[ks][7]=a1.w;
  }
  f32x4 acc[8]; mfma_core(av, bhi, blo, lane, acc);
  biasrelu(acc, bias, l15, true);

  #pragma unroll
  for (int ct = 0; ct < 8; ++ct){
    float s = 0.f, q2 = 0.f;
    #pragma unroll
    for (int q = 0; q < 4; ++q){
      float v = acc[ct][q];
      s += v; q2 = fmaf(v, v, q2);
    }
    s  += __shfl_xor(s, 16, 64);  s  += __shfl_xor(s, 32, 64);
    q2 += __shfl_xor(q2, 16, 64); q2 += __shfl_xor(q2, 32, 64);
    if (kg == 0){
      const int slot = (blockIdx.x & 7)*256;
      atomicAdd(&part2[slot + ct*16 + l15], s);
      atomicAdd(&part2[slot + 128 + ct*16 + l15], q2);
    }
  }

  #pragma unroll
  for (int ct = 0; ct < 8; ++ct)
    #pragma unroll
    for (int q = 0; q < 4; ++q)
      t[(rb + kg*4 + q)*HD + ct*16 + l15] = acc[ct][q];
}

// ---------------- MFMA GEMM with fused pre/post ops (1 wave/block) ----------------
// ZSTEP: zc/zp/p loads hoisted BEFORE the MFMA stream (latency overlap).
template<bool RELU, bool BN_IN, bool XH_IN, bool NORM_OUT,
         bool WRITE_HB, bool WRITE_OUT, bool ZSTEP, bool ZFIRST>
__global__ __launch_bounds__(64) void mgemm_k(const float* __restrict__ A,
    const bf16x8* __restrict__ bhi, const bf16x8* __restrict__ blo,
    const float* __restrict__ bias, const float* __restrict__ scale,
    const float* __restrict__ shift, float* __restrict__ out,
    unsigned short* __restrict__ hbout, float* __restrict__ zout, float scaling,
    const float* __restrict__ zpin, const float* __restrict__ zcin,
    const float* __restrict__ pvec)
{
  const int lane = threadIdx.x;
  const int l15 = lane & 15, kg = lane >> 4;
  const long rb = (long)blockIdx.x*16;   // 2500*16 = 40000 exact

  float av[4][8];
  loadA_g(A, rb, l15, kg, av);

  // ---- ZSTEP operand prefetch (issued before the MFMA stream; consumed after) ----
  float zc_a[4][8], zp_a[4][8], pvr[8];
  if constexpr (ZSTEP){
    #pragma unroll
    for (int q = 0; q < 4; ++q){
      const long row = rb + kg*4 + q;
      #pragma unroll
      for (int ct = 0; ct < 8; ++ct)
        zc_a[q][ct] = zcin[row*HD + ct*16 + l15];
    }
    if constexpr (!ZFIRST){
      #pragma unroll
      for (int q = 0; q < 4; ++q){
        const long row = rb + kg*4 + q;
        #pragma unroll
        for (int ct = 0; ct < 8; ++ct)
          zp_a[q][ct] = zpin[row*HD + ct*16 + l15];
      }
    }
    #pragma unroll
    for (int ct = 0; ct < 8; ++ct) pvr[ct] = pvec[ct*16 + l15];
  }

  if (BN_IN){
    #pragma unroll
    for (int ks = 0; ks < 4; ++ks){
      const int k0 = ks*32 + kg*8;
      float4 s0 = *(const float4*)(scale + k0);
      float4 s1 = *(const float4*)(scale + k0 + 4);
      float4 h0 = *(const float4*)(shift + k0);
      float4 h1 = *(const float4*)(shift + k0 + 4);
      float sc[8] = {s0.x,s0.y,s0.z,s0.w,s1.x,s1.y,s1.z,s1.w};
      float sh[8] = {h0.x,h0.y,h0.z,h0.w,h1.x,h1.y,h1.z,h1.w};
      #pragma unroll
      for (int j = 0; j < 8; ++j)
        av[ks][j] = fmaf(av[ks][j], sc[j], sh[j]);
    }
  }
  if (XH_IN){
    float ss = 0.f;
    #pragma unroll
    for (int ks = 0; ks < 4; ++ks)
      #pragma unroll
      for (int j = 0; j < 8; ++j)
        ss = fmaf(av[ks][j], av[ks][j], ss);
    ss += __shfl_xor(ss, 16, 64);
    ss += __shfl_xor(ss, 32, 64);
    float n = sqrtf(ss);
    float yn = fmaxf(n, MINN);
    float c = fminf(yn, 1.0f);
    float at = 0.5f*logf((1.0f + c)/(1.0f - c));
    float scx = at / yn;
    #pragma unroll
    for (int ks = 0; ks < 4; ++ks)
      #pragma unroll
      for (int j = 0; j < 8; ++j)
        av[ks][j] *= scx;
  }

  f32x4 acc[8];
  mfma_core(av, bhi, blo, lane, acc);
  biasrelu(acc, bias, l15, RELU);

  if (NORM_OUT){
    float ss[4] = {0.f,0.f,0.f,0.f};
    #pragma unroll
    for (int ct = 0; ct < 8; ++ct)
      #pragma unroll
      for (int q = 0; q < 4; ++q)
        ss[q] = fmaf(acc[ct][q], acc[ct][q], ss[q]);
    #pragma unroll
    for (int q = 0; q < 4; ++q){
      #pragma unroll
      for (int m = 1; m < 16; m <<= 1) ss[q] += __shfl_xor(ss[q], m, 64);
      ss[q] = 1.0f / fmaxf(sqrtf(ss[q]), 1e-12f);
    }
    #pragma unroll
    for (int ct = 0; ct < 8; ++ct)
      #pragma unroll
      for (int q = 0; q < 4; ++q)
        acc[ct][q] *= ss[q];
  }

  if constexpr (ZSTEP){
    // q_ = p/|p| is row-independent
    float pq = 0.f;
    #pragma unroll
    for (int ct = 0; ct < 8; ++ct) pq = fmaf(pvr[ct], pvr[ct], pq);
    pq = red16(pq);
    float qi = 1.0f / fmaxf(sqrtf(pq), MINN);
    #pragma unroll
    for (int ct = 0; ct < 8; ++ct) pvr[ct] *= qi;

    #pragma unroll
    for (int q = 0; q < 4; ++q){
      const long row = rb + kg*4 + q;
      float zc[8], zp[8];
      #pragma unroll
      for (int ct = 0; ct < 8; ++ct) zc[ct] = zc_a[q][ct];
      if constexpr (!ZFIRST){
        #pragma unroll
        for (int ct = 0; ct < 8; ++ct) zp[ct] = zp_a[q][ct];
      } else {
        #pragma unroll
        for (int ct = 0; ct < 8; ++ct) zp[ct] = 0.f;
      }
      float hh = 0.f, cc = 0.f;
      #pragma unroll
      for (int ct = 0; ct < 8; ++ct){
        hh = fmaf(acc[ct][q], acc[ct][q], hh);
        cc = fmaf(zc[ct], zc[ct], cc);
      }
      hh = red16(hh); cc = red16(cc);
      float zs = scaling / sqrtf(hh);
      float di = 1.0f / fmaxf(cc, MINN);
      float r2 = cc*di*di - 1.0f;
      float a[8], u[8]; float uu = 0.f;
      #pragma unroll
      for (int ct = 0; ct < 8; ++ct){
        a[ct] = zc[ct]*di;
        u[ct] = zp[ct] - a[ct];
        uu = fmaf(u[ct], u[ct], uu);
      }
      uu = red16(uu);
      float f = r2 / fmaxf(uu, MINN);
      float zpar[8]; float pn2 = 0.f;
      #pragma unroll
      for (int ct = 0; ct < 8; ++ct){
        zpar[ct] = fmaf(f, u[ct], a[ct]);
        pn2 = fmaf(zpar[ct], zpar[ct], pn2);
      }
      pn2 = red16(pn2);
      float pinv = 1.0f / fmaxf(sqrtf(pn2), MINN);
      float rv[8], zch[8]; float rz = 0.f, rr = 0.f;
      #pragma unroll
      for (int ct = 0; ct < 8; ++ct){
        zch[ct] = acc[ct][q]*zs;
        rv[ct] = pvr[ct] - zpar[ct]*pinv;
        rz = fmaf(rv[ct], zch[ct], rz);
        rr = fmaf(rv[ct], rv[ct], rr);
      }
      rz = red16(rz); rr = red16(rr);
      float mm = rz / rr;
      float u2[8]; float uu2 = 0.f;
      #pragma unroll
      for (int ct = 0; ct < 8; ++ct){
        float z2 = fmaf(-2.0f*mm, rv[ct], zch[ct]);
        u2[ct] = z2 - a[ct];
        uu2 = fmaf(u2[ct], u2[ct], uu2);
      }
      uu2 = red16(uu2);
      float f2 = r2 / fmaxf(uu2, MINN);
      #pragma unroll
      for (int ct = 0; ct < 8; ++ct)
        zout[row*HD + ct*16 + l15] = fmaf(f2, u2[ct], a[ct]);
    }
  }

  if constexpr (WRITE_OUT || WRITE_HB){
    #pragma unroll
    for (int ct = 0; ct < 8; ++ct)
      #pragma unroll
      for (int q = 0; q < 4; ++q){
        float v = acc[ct][q];
        long row = rb + kg*4 + q;
        if (WRITE_OUT) out[row*HD + ct*16 + l15] = v;
        if (WRITE_HB) hbout[row*HD + ct*16 + l15] = (unsigned short)f2bf(v);
      }
  }
}

// ---------------- BN finalize: part2[8][256] -> scale/shift; re-zero part2 ----------
__global__ __launch_bounds__(256) void bnfin_k(float* __restrict__ part2,
    const float* __restrict__ g, const float* __restrict__ b,
    float* __restrict__ scale, float* __restrict__ shift){
  __shared__ float sm[256];
  float tot = 0.f;
  #pragma unroll
  for (int r = 0; r < 8; ++r) tot += part2[r*256 + threadIdx.x];
  sm[threadIdx.x] = tot;
  __syncthreads();
  if (threadIdx.x < 128){
    int c = threadIdx.x;
    float s = sm[c], q = sm[c + 128];
    float mu  = s * (1.0f/NN);
    float var = q * (1.0f/NN) - mu*mu;
    float istd = rsqrtf(var + 1e-5f);
    float scv = g[c]*istd;
    scale[c] = scv;
    shift[c] = fmaf(-mu, scv, b[c]);
  }
  #pragma unroll
  for (int r = 0; r < 8; ++r) part2[r*256 + threadIdx.x] = 0.f;
}

extern "C" void kernel_launch(void* const* d_in, const int* in_sizes, int n_in,
                              void* d_out, int out_size, void* d_ws, size_t ws_size,
                              hipStream_t stream) {
  const float* x       = (const float*)d_in[0];
  const int*   ei      = (const int*)  d_in[1];
  const float* fc0_w   = (const float*)d_in[2];
  const float* fc0_b   = (const float*)d_in[3];
  const float* w1      = (const float*)d_in[4];
  const float* b1      = (const float*)d_in[5];
  const float* gamma   = (const float*)d_in[6];
  const float* beta    = (const float*)d_in[7];
  const float* w2      = (const float*)d_in[8];
  const float* b2      = (const float*)d_in[9];
  const float* fco_w   = (const float*)d_in[10];
  const float* fco_b   = (const float*)d_in[11];
  const float* p       = (const float*)d_in[12];

  float* out = (float*)d_out;
  float* ws  = (float*)d_ws;

  float* h     = ws;                     // [NN*HD] f32
  float* zA    = h   + (size_t)NN*HD;
  float* zB    = zA  + (size_t)NN*HD;
  float* part2 = zB  + (size_t)NN*HD;    // [8*256]
  float* scale = part2 + 8*256;          // [128]
  float* shift = scale + 128;            // [128]
  bf16x8* bhi  = (bf16x8*)(shift + 128); // [8*2048]
  bf16x8* blo  = bhi + 8*2048;           // [8*2048]
  unsigned short* hb = (unsigned short*)(blo + 8*2048); // [NN*HD] bf16 mirror
  int* cnt     = (int*)(hb + (size_t)NN*HD);
  int* ptr     = cnt + NN;               // [NN+1]
  int* fil     = ptr + NN + 1;           // [NN]
  unsigned short* eidx = (unsigned short*)(fil + NN);   // [NE] (u16 src ids)
  int* locpre  = (int*)(eidx + NE);      // [NSB*256]
  int* btot    = locpre + NSB*256;       // [NSB]
  float* t = out;                        // reuse d_out as the w1-activation buffer

  const int* src = ei;
  const int* dst = ei + NE;
  const float scaling = tanhf(0.5f);

  // K1: weight prep + zero cnt/part2
  zero_prep_k<<<417, 64, 0, stream>>>(fc0_w, w1, w2, fco_w, bhi, blo, cnt, part2);

  // K2: fc0 tiles (h, hb, zinit->zB) + edge histogram
  fc0hist_k<<<GB + HB_BLK, 64, 0, stream>>>(x, dst, cnt, bhi, blo, fc0_b,
                                            h, hb, zB, scaling);

  // K3-K5: scan + fill (CSR by dst)
  scan1_k<<<NSB, 256, 0, stream>>>(cnt, locpre, btot);
  scan23_k<<<NSB, 256, 0, stream>>>(btot, locpre, ptr, fil);
  fill_k<<<512, 256, 0, stream>>>(src, dst, fil, eidx, NE);

  float* zprev = zA; float* zcur = zB;

  for (int i = 0; i < 3; ++i) {
    // t = relu((h + agg(h)) @ w1^T + b1); 4-wave gather; stats -> atomic part2
    gw1_k<<<GB, 256, 0, stream>>>(
        h, bhi + (1+i)*2048, blo + (1+i)*2048, b1 + i*HD, t, part2,
        (const uint4*)hb, ptr, eidx);
    bnfin_k<<<1, 256, 0, stream>>>(part2, gamma + i*HD, beta + i*HD, scale, shift);
    // h = relu( BN(t) @ w2^T + b2 ) + fused hyperbolic z-step (hoisted z loads).
    if (i == 0)
      mgemm_k<true,true,false,false,true,true,true,true>
          <<<GB, 64, 0, stream>>>(
          t, bhi + 4*2048, blo + 4*2048, b2, scale, shift, h, hb,
          zprev, scaling, zprev, zcur, p);
    else if (i == 1)
      mgemm_k<true,true,false,false,true,true,true,false>
          <<<GB, 64, 0, stream>>>(
          t, bhi + 5*2048, blo + 5*2048, b2 + HD, scale, shift, h, hb,
          zprev, scaling, zprev, zcur, p);
    else
      mgemm_k<true,true,false,false,false,false,true,false>
          <<<GB, 64, 0, stream>>>(
          t, bhi + 6*2048, blo + 6*2048, b2 + 2*HD, scale, shift, h, nullptr,
          zprev, scaling, zprev, zcur, p);
    float* tmp = zprev; zprev = zcur; zcur = tmp;
  }

  // out = normalize( logmap0(z_cur) @ fc_out^T + fc_out_b )
  mgemm_k<false,false,true,true,false,true,false,false>
      <<<GB, 64, 0, stream>>>(
      zcur, bhi + 7*2048, blo + 7*2048, fco_b, nullptr, nullptr, out,
      nullptr, nullptr, 0.f, nullptr, nullptr, nullptr);
}